// Round 4
// baseline (6478.385 us; speedup 1.0000x reference)
//
#include <hip/hip_runtime.h>

// Fused flash-style softmax(Q V^T) V, B=4, NQ=NK=4096, D=1024, fp32 in/out.
// Round 4: round-3 verified structure, with the 32KB spart partial buffer
// replaced by an 8KB double-buffered LDS accumulator reduced via ds_add_f32
// atomics. LDS ~76.5KB -> 2 blocks/CU so barrier stalls overlap across blocks.
// - Block = 32 q-rows, 8 waves, wave w owns d-slice [128w,128w+128).
// - S^T = mfma(V, Q) swapped so both operands are d-contiguous (fp16, 1 product).
// - V staged per-wave in LDS (vhi_off swizzle), PV B-frags via scalar u16 reads.

#define NB   4
#define NQL  4096
#define NKL  4096
#define DIM  1024
#define BQ   32
#define BK   32
#define NW   8
#define DSL  128
#define NT   (NKL / BK)
#define LOG2E 1.44269504088896340736f
#define SRW  33  // sred row stride (f32): (q+k)&31 bank spread, conflict-free softmax reads

typedef float f32x4 __attribute__((ext_vector_type(4)));
typedef _Float16 f16x8 __attribute__((ext_vector_type(8)));
typedef short s16x8 __attribute__((ext_vector_type(8)));

union Frag { f16x8 v; s16x8 s; _Float16 h[8]; };

// V LDS addressing (round-1 verified): wave-private [BK][DSL] f16 tile,
// slot-swizzled so b128 stage-writes are bank-optimal and u16 PV reads OK.
__device__ __forceinline__ int vhi_off(int k, int dloc) {  // byte offset in wave region
    int slot = ((k & 7) + 2 * ((k >> 3) & 3)) & 7;
    return k * (DSL * 2) + ((dloc * 2) ^ (slot * 16));
}

__global__ __launch_bounds__(512, 4)
void attn_f16(const float* __restrict__ Qg, const float* __restrict__ Vg,
              float* __restrict__ Og) {
    __shared__ __align__(16) short vhi_s[NW * BK * DSL];  // 64 KB
    __shared__ float sred[2][BQ][SRW];                    // 8.25 KB, atomic S^T accum
    __shared__ __align__(16) short pbuf[BQ * BK];         // 2 KB (fp16 P)
    __shared__ float mrun[BQ], lrun[BQ], arun[BQ];

    const int tid = (int)threadIdx.x;
    const int l   = tid & 63;
    const int w   = tid >> 6;
    const int l15 = l & 15;
    const int lg  = l >> 4;

    const int b  = (int)blockIdx.x >> 7;
    const int qt = (int)blockIdx.x & 127;
    const int q0 = qt * BQ;
    const int dw = w * DSL;

    if (tid < BQ) { mrun[tid] = -3e38f; lrun[tid] = 0.f; arun[tid] = 1.f; }
    // zero both sred buffers
    {
        float* sf = &sred[0][0][0];
        for (int i = tid; i < 2 * BQ * SRW; i += 512) sf[i] = 0.f;
    }

    // Q fragments (B-operand): lane holds Q[q0+qb*16+l15][dw+dc*32+lg*8 .. +7] fp16
    f16x8 qf[2][4];
#pragma unroll
    for (int qb = 0; qb < 2; ++qb)
#pragma unroll
        for (int dc = 0; dc < 4; ++dc) {
            const float* qp = Qg + (size_t)(b * NQL + q0 + qb * 16 + l15) * DIM
                            + dw + dc * 32 + lg * 8;
            f32x4 x0 = *(const f32x4*)qp;
            f32x4 x1 = *(const f32x4*)(qp + 4);
            f16x8 a;
#pragma unroll
            for (int j = 0; j < 4; ++j) { a[j] = (_Float16)x0[j]; a[j + 4] = (_Float16)x1[j]; }
            qf[qb][dc] = a;
        }

    f32x4 oacc[2][8];
#pragma unroll
    for (int qb = 0; qb < 2; ++qb)
#pragma unroll
        for (int dg = 0; dg < 8; ++dg)
            oacc[qb][dg] = (f32x4){0.f, 0.f, 0.f, 0.f};

    char* vbase = (char*)&vhi_s[w * (BK * DSL)];

    f32x4 sacc[2][2];
    f32x4 hA[4][2], hB[4][2];  // register prefetch buffers: half-tile each

    auto loadhalf = [&](f32x4 (&buf)[4][2], int kt_, int kb) {
        const float* vp = Vg + (size_t)(b * NKL + kt_ * BK + kb * 16 + l15) * DIM
                        + dw + lg * 8;
#pragma unroll
        for (int dc = 0; dc < 4; ++dc) {
            buf[dc][0] = *(const f32x4*)(vp + dc * 32);
            buf[dc][1] = *(const f32x4*)(vp + dc * 32 + 4);
        }
    };

    auto computehalf = [&](f32x4 (&buf)[4][2], int kb) {
        const int kvl = kb * 16 + l15;
#pragma unroll
        for (int dc = 0; dc < 4; ++dc) {
            Frag fa;
#pragma unroll
            for (int j = 0; j < 4; ++j) {
                fa.h[j]     = (_Float16)buf[dc][0][j];
                fa.h[j + 4] = (_Float16)buf[dc][1][j];
            }
            *(s16x8*)(vbase + vhi_off(kvl, dc * 32 + lg * 8)) = fa.s;
            sacc[kb][0] = __builtin_amdgcn_mfma_f32_16x16x32_f16(fa.v, qf[0][dc], sacc[kb][0], 0, 0, 0);
            sacc[kb][1] = __builtin_amdgcn_mfma_f32_16x16x32_f16(fa.v, qf[1][dc], sacc[kb][1], 0, 0, 0);
        }
    };

    // softmax lane assignment: q = 4w+lg, k = l15 and l15+16
    const int qsm = 4 * w + lg;

    loadhalf(hA, 0, 0);
    loadhalf(hB, 0, 1);
    __syncthreads();

    for (int kt = 0; kt < NT; ++kt) {
        const int cur = kt & 1;
#pragma unroll
        for (int kb = 0; kb < 2; ++kb)
#pragma unroll
            for (int qb = 0; qb < 2; ++qb)
                sacc[kb][qb] = (f32x4){0.f, 0.f, 0.f, 0.f};

        const int ktn = (kt + 1 < NT) ? kt + 1 : NT - 1;
        computehalf(hA, 0);
        loadhalf(hA, ktn, 0);   // next tile, in flight over hB compute + softmax + PV
        computehalf(hB, 1);
        loadhalf(hB, ktn, 1);

        // Cross-wave S^T reduction via LDS atomics
        // (acc layout: row k = kb*16+4*lg+r, col q = qb*16+l15)
#pragma unroll
        for (int kb = 0; kb < 2; ++kb)
#pragma unroll
            for (int qb = 0; qb < 2; ++qb)
#pragma unroll
                for (int r = 0; r < 4; ++r) {
                    int k = kb * 16 + lg * 4 + r;
                    int q = qb * 16 + l15;
                    atomicAdd(&sred[cur][q][k], sacc[kb][qb][r]);
                }
        __syncthreads();  // B1: all atomic adds visible

        // Phase 2: online softmax for q = qsm (full scores now in sred[cur])
        {
            float s0 = sred[cur][qsm][l15];
            float s1 = sred[cur][qsm][l15 + 16];
            float mloc = fmaxf(s0, s1);
#pragma unroll
            for (int off = 1; off < 16; off <<= 1)
                mloc = fmaxf(mloc, __shfl_xor(mloc, off));
            float mold = mrun[qsm];
            float mnew = fmaxf(mold, mloc);
            float p0 = exp2f((s0 - mnew) * LOG2E);
            float p1 = exp2f((s1 - mnew) * LOG2E);
            float rs = p0 + p1;
#pragma unroll
            for (int off = 1; off < 16; off <<= 1)
                rs += __shfl_xor(rs, off);
            float alpha = exp2f((mold - mnew) * LOG2E);
            if (l15 == 0) {
                mrun[qsm] = mnew;
                lrun[qsm] = alpha * lrun[qsm] + rs;
                arun[qsm] = alpha;
            }
            pbuf[qsm * BK + l15]      = __builtin_bit_cast(short, (_Float16)p0);
            pbuf[qsm * BK + l15 + 16] = __builtin_bit_cast(short, (_Float16)p1);
        }
        __syncthreads();  // B2: P/alpha/m/l visible; sred[cur] reads complete

        // Phase 3: zero sred[cur] for tile kt+2, rescale O, then O += P * V
        {
            float* sf = &sred[cur][0][0];
            for (int i = tid; i < BQ * SRW; i += 512) sf[i] = 0.f;
        }

        float av[2][4];
#pragma unroll
        for (int qb = 0; qb < 2; ++qb)
#pragma unroll
            for (int r = 0; r < 4; ++r)
                av[qb][r] = arun[qb * 16 + lg * 4 + r];
#pragma unroll
        for (int qb = 0; qb < 2; ++qb)
#pragma unroll
            for (int dg = 0; dg < 8; ++dg)
#pragma unroll
                for (int r = 0; r < 4; ++r)
                    oacc[qb][dg][r] *= av[qb][r];

        Frag pf[2];
#pragma unroll
        for (int qb = 0; qb < 2; ++qb)
            pf[qb].s = *(const s16x8*)(pbuf + (qb * 16 + l15) * BK + lg * 8);

#pragma unroll
        for (int dg = 0; dg < 8; ++dg) {
            Frag bf;
#pragma unroll
            for (int j = 0; j < 8; ++j) {
                int k = lg * 8 + j;
                bf.h[j] = *(const _Float16*)(vbase + vhi_off(k, dg * 16 + l15));
            }
#pragma unroll
            for (int qb = 0; qb < 2; ++qb)
                oacc[qb][dg] = __builtin_amdgcn_mfma_f32_16x16x32_f16(
                    pf[qb].v, bf.v, oacc[qb][dg], 0, 0, 0);
        }
    }

    // Epilogue: normalize by l, store fp32
#pragma unroll
    for (int qb = 0; qb < 2; ++qb) {
        float il[4];
#pragma unroll
        for (int r = 0; r < 4; ++r)
            il[r] = 1.0f / lrun[qb * 16 + lg * 4 + r];
#pragma unroll
        for (int dg = 0; dg < 8; ++dg)
#pragma unroll
            for (int r = 0; r < 4; ++r) {
                int q = q0 + qb * 16 + lg * 4 + r;
                int d = dw + dg * 16 + l15;
                Og[(size_t)(b * NQL + q) * DIM + d] = oacc[qb][dg][r] * il[r];
            }
    }
}

extern "C" void kernel_launch(void* const* d_in, const int* in_sizes, int n_in,
                              void* d_out, int out_size, void* d_ws, size_t ws_size,
                              hipStream_t stream) {
    const float* Q = (const float*)d_in[0];
    const float* V = (const float*)d_in[1];
    float* O = (float*)d_out;
    (void)in_sizes; (void)n_in; (void)out_size; (void)d_ws; (void)ws_size;
    dim3 grid(NB * (NQL / BQ));  // 512 blocks
    dim3 block(NW * 64);         // 512 threads
    attn_f16<<<grid, block, 0, stream>>>(Q, V, O);
}

// Round 6
// 4104.795 us; speedup vs baseline: 1.5782x; 1.5782x over previous
//
#include <hip/hip_runtime.h>

// Fused flash-style softmax(Q V^T) V, B=4, NQ=NK=4096, D=1024, fp32 in/out.
// Round 6 == round 5 (infra failure, untested): chain compression.
//  - fp16 single-product MFMA (r3-verified numerics), atomic sred reduction
//    (r4-verified), BQ=32/BK=32/NW=8, wave w owns d-slice [128w,128w+128).
//  - __launch_bounds__(512,2): 256-VGPR budget so next-tile V prefetch regs
//    (64 VGPR) stay live (r3's cap of 128 made the compiler sink the loads).
//  - V loads for tile t+1 issued right after B1 (softmax window).
//  - B2 is a raw "s_waitcnt lgkmcnt(0); s_barrier" (NO vmcnt drain) so the
//    prefetch loads stay in flight across it; they are consumed next-tile
//    QK^T, ~1700 cycles after issue.
//  - pbuf 16B-block XOR swizzle kills the 8-way conflict on P b128 reads.

#define NB   4
#define NQL  4096
#define NKL  4096
#define DIM  1024
#define BQ   32
#define BK   32
#define NW   8
#define DSL  128
#define NT   (NKL / BK)
#define LOG2E 1.44269504088896340736f
#define SRW  33  // sred row stride (f32)

typedef float f32x4 __attribute__((ext_vector_type(4)));
typedef _Float16 f16x8 __attribute__((ext_vector_type(8)));
typedef short s16x8 __attribute__((ext_vector_type(8)));

union Frag { f16x8 v; s16x8 s; _Float16 h[8]; };

// V LDS addressing (r1-verified): wave-private [BK][DSL] f16 tile, slot-swizzled.
__device__ __forceinline__ int vhi_off(int k, int dloc) {  // byte offset in wave region
    int slot = ((k & 7) + 2 * ((k >> 3) & 3)) & 7;
    return k * (DSL * 2) + ((dloc * 2) ^ (slot * 16));
}

// pbuf 16B-block swizzle: row q, 4 blocks of 8 shorts; block b stored at b ^ swz(q).
__device__ __forceinline__ int psw(int q) { return (q & 3) ^ ((q >> 2) & 3); }

// Barrier that does NOT drain vmcnt: LDS visibility only.
__device__ __forceinline__ void barrier_keep_vmem() {
    asm volatile("s_waitcnt lgkmcnt(0)\n\ts_barrier" ::: "memory");
}

__global__ __launch_bounds__(512, 2)
void attn_f16(const float* __restrict__ Qg, const float* __restrict__ Vg,
              float* __restrict__ Og) {
    __shared__ __align__(16) short vhi_s[NW * BK * DSL];  // 64 KB
    __shared__ float sred[2][BQ][SRW];                    // 8.25 KB, atomic S^T accum
    __shared__ __align__(16) short pbuf[BQ * BK];         // 2 KB (fp16 P, swizzled)
    __shared__ float mrun[BQ], lrun[BQ], arun[BQ];

    const int tid = (int)threadIdx.x;
    const int l   = tid & 63;
    const int w   = tid >> 6;
    const int l15 = l & 15;
    const int lg  = l >> 4;

    const int b  = (int)blockIdx.x >> 7;
    const int qt = (int)blockIdx.x & 127;
    const int q0 = qt * BQ;
    const int dw = w * DSL;

    if (tid < BQ) { mrun[tid] = -3e38f; lrun[tid] = 0.f; arun[tid] = 1.f; }
    {
        float* sf = &sred[0][0][0];
        for (int i = tid; i < 2 * BQ * SRW; i += 512) sf[i] = 0.f;
    }

    // Q fragments (B-operand): lane holds Q[q0+qb*16+l15][dw+dc*32+lg*8 .. +7] fp16
    f16x8 qf[2][4];
#pragma unroll
    for (int qb = 0; qb < 2; ++qb)
#pragma unroll
        for (int dc = 0; dc < 4; ++dc) {
            const float* qp = Qg + (size_t)(b * NQL + q0 + qb * 16 + l15) * DIM
                            + dw + dc * 32 + lg * 8;
            f32x4 x0 = *(const f32x4*)qp;
            f32x4 x1 = *(const f32x4*)(qp + 4);
            f16x8 a;
#pragma unroll
            for (int j = 0; j < 4; ++j) { a[j] = (_Float16)x0[j]; a[j + 4] = (_Float16)x1[j]; }
            qf[qb][dc] = a;
        }

    f32x4 oacc[2][8];
#pragma unroll
    for (int qb = 0; qb < 2; ++qb)
#pragma unroll
        for (int dg = 0; dg < 8; ++dg)
            oacc[qb][dg] = (f32x4){0.f, 0.f, 0.f, 0.f};

    char* vbase = (char*)&vhi_s[w * (BK * DSL)];

    f32x4 sacc[2][2];
    f32x4 hA[4][2], hB[4][2];  // prefetch buffers (32 VGPR each), live across B2

    auto loadhalf = [&](f32x4 (&buf)[4][2], int kt_, int kb) {
        const float* vp = Vg + (size_t)(b * NKL + kt_ * BK + kb * 16 + l15) * DIM
                        + dw + lg * 8;
#pragma unroll
        for (int dc = 0; dc < 4; ++dc) {
            buf[dc][0] = *(const f32x4*)(vp + dc * 32);
            buf[dc][1] = *(const f32x4*)(vp + dc * 32 + 4);
        }
    };

    auto computehalf = [&](f32x4 (&buf)[4][2], int kb) {
        const int kvl = kb * 16 + l15;
#pragma unroll
        for (int dc = 0; dc < 4; ++dc) {
            Frag fa;
#pragma unroll
            for (int j = 0; j < 4; ++j) {
                fa.h[j]     = (_Float16)buf[dc][0][j];
                fa.h[j + 4] = (_Float16)buf[dc][1][j];
            }
            *(s16x8*)(vbase + vhi_off(kvl, dc * 32 + lg * 8)) = fa.s;
            sacc[kb][0] = __builtin_amdgcn_mfma_f32_16x16x32_f16(fa.v, qf[0][dc], sacc[kb][0], 0, 0, 0);
            sacc[kb][1] = __builtin_amdgcn_mfma_f32_16x16x32_f16(fa.v, qf[1][dc], sacc[kb][1], 0, 0, 0);
        }
    };

    // softmax lane assignment: q = 4w+lg, k = l15 and l15+16
    const int qsm = 4 * w + lg;

    loadhalf(hA, 0, 0);
    loadhalf(hB, 0, 1);
    __syncthreads();

    for (int kt = 0; kt < NT; ++kt) {
        const int cur = kt & 1;
#pragma unroll
        for (int kb = 0; kb < 2; ++kb)
#pragma unroll
            for (int qb = 0; qb < 2; ++qb)
                sacc[kb][qb] = (f32x4){0.f, 0.f, 0.f, 0.f};

        // QK^T on prefetched registers; stages vhi f16 to LDS as a side effect
        computehalf(hA, 0);
        computehalf(hB, 1);

        // Cross-wave S^T reduction via LDS atomics
        // (acc layout: row k = kb*16+4*lg+r, col q = qb*16+l15)
#pragma unroll
        for (int kb = 0; kb < 2; ++kb)
#pragma unroll
            for (int qb = 0; qb < 2; ++qb)
#pragma unroll
                for (int r = 0; r < 4; ++r) {
                    int k = kb * 16 + lg * 4 + r;
                    int q = qb * 16 + l15;
                    atomicAdd(&sred[cur][q][k], sacc[kb][qb][r]);
                }
        __syncthreads();  // B1 (nothing in vmem flight here)

        // Issue next-tile V loads NOW: they fly through softmax + raw B2 + PV,
        // consumed at next iteration's computehalf (~1700 cyc of cover).
        const int ktn = (kt + 1 < NT) ? kt + 1 : NT - 1;
        loadhalf(hA, ktn, 0);
        loadhalf(hB, ktn, 1);

        // Phase 2: online softmax for q = qsm (full scores in sred[cur])
        {
            float s0 = sred[cur][qsm][l15];
            float s1 = sred[cur][qsm][l15 + 16];
            float mloc = fmaxf(s0, s1);
#pragma unroll
            for (int off = 1; off < 16; off <<= 1)
                mloc = fmaxf(mloc, __shfl_xor(mloc, off));
            float mold = mrun[qsm];
            float mnew = fmaxf(mold, mloc);
            float p0 = exp2f((s0 - mnew) * LOG2E);
            float p1 = exp2f((s1 - mnew) * LOG2E);
            float rs = p0 + p1;
#pragma unroll
            for (int off = 1; off < 16; off <<= 1)
                rs += __shfl_xor(rs, off);
            float alpha = exp2f((mold - mnew) * LOG2E);
            if (l15 == 0) {
                mrun[qsm] = mnew;
                lrun[qsm] = alpha * lrun[qsm] + rs;
                arun[qsm] = alpha;
            }
            // swizzled P store: block b' = (k>>3) ^ psw(q), offset k&7 preserved
            const int sw = psw(qsm);
            pbuf[qsm * BK + (((l15 >> 3) ^ sw) << 3) + (l15 & 7)] =
                __builtin_bit_cast(short, (_Float16)p0);
            pbuf[qsm * BK + ((((l15 >> 3) + 2) ^ sw) << 3) + (l15 & 7)] =
                __builtin_bit_cast(short, (_Float16)p1);
        }
        barrier_keep_vmem();  // B2: LDS visibility only; V loads stay in flight

        // Phase 3: zero sred[cur] (for tile kt+2), rescale O, then O += P * V
        {
            float* sf = &sred[cur][0][0];
            for (int i = tid; i < BQ * SRW; i += 512) sf[i] = 0.f;
        }

        float av[2][4];
#pragma unroll
        for (int qb = 0; qb < 2; ++qb)
#pragma unroll
            for (int r = 0; r < 4; ++r)
                av[qb][r] = arun[qb * 16 + lg * 4 + r];
#pragma unroll
        for (int qb = 0; qb < 2; ++qb)
#pragma unroll
            for (int dg = 0; dg < 8; ++dg)
#pragma unroll
                for (int r = 0; r < 4; ++r)
                    oacc[qb][dg][r] *= av[qb][r];

        Frag pf[2];
#pragma unroll
        for (int qb = 0; qb < 2; ++qb) {
            const int q = qb * 16 + l15;
            pf[qb].s = *(const s16x8*)(pbuf + q * BK + ((lg ^ psw(q)) << 3));
        }

#pragma unroll
        for (int dg = 0; dg < 8; ++dg) {
            Frag bf;
#pragma unroll
            for (int j = 0; j < 8; ++j) {
                int k = lg * 8 + j;
                bf.h[j] = *(const _Float16*)(vbase + vhi_off(k, dg * 16 + l15));
            }
#pragma unroll
            for (int qb = 0; qb < 2; ++qb)
                oacc[qb][dg] = __builtin_amdgcn_mfma_f32_16x16x32_f16(
                    pf[qb].v, bf.v, oacc[qb][dg], 0, 0, 0);
        }
    }

    // Epilogue: normalize by l, store fp32
#pragma unroll
    for (int qb = 0; qb < 2; ++qb) {
        float il[4];
#pragma unroll
        for (int r = 0; r < 4; ++r)
            il[r] = 1.0f / lrun[qb * 16 + lg * 4 + r];
#pragma unroll
        for (int dg = 0; dg < 8; ++dg)
#pragma unroll
            for (int r = 0; r < 4; ++r) {
                int q = q0 + qb * 16 + lg * 4 + r;
                int d = dw + dg * 16 + l15;
                Og[(size_t)(b * NQL + q) * DIM + d] = oacc[qb][dg][r] * il[r];
            }
    }
}

extern "C" void kernel_launch(void* const* d_in, const int* in_sizes, int n_in,
                              void* d_out, int out_size, void* d_ws, size_t ws_size,
                              hipStream_t stream) {
    const float* Q = (const float*)d_in[0];
    const float* V = (const float*)d_in[1];
    float* O = (float*)d_out;
    (void)in_sizes; (void)n_in; (void)out_size; (void)d_ws; (void)ws_size;
    dim3 grid(NB * (NQL / BQ));  // 512 blocks
    dim3 block(NW * 64);         // 512 threads
    attn_f16<<<grid, block, 0, stream>>>(Q, V, O);
}

// Round 9
// 1242.604 us; speedup vs baseline: 5.2136x; 3.3034x over previous
//
#include <hip/hip_runtime.h>

// Fused flash-style softmax(Q V^T) V, B=4, NQ=NK=4096, D=1024, fp32 in/out.
// Round 9 == round 8 (infra failure on pod, untested): r3/r6-verified
// structure (fp16 single-product, spart reduction, __shfl_xor softmax, scalar
// u16 PV reads). NO tr-read, NO DPP (both failed silicon-verification twice).
// Changes vs r3:
//  - amdgpu_waves_per_eu(2,2): allocator may use up to 256 VGPRs so the
//    next-tile V prefetch (hA/hB, 64 VGPR) stays live (r3/r6: VGPR=128 ->
//    loads sunk to use sites, prefetch dead).
//  - both barriers are raw lgkm-only (s_waitcnt lgkmcnt(0); s_barrier):
//    prefetch vmem stays in flight across B1+B2 (~4-6k cyc of cover).
//  - spart: b128 XOR-swizzled writes (2 lanes/bank), b64 pair reads
//    (16->8 LDS instrs per lane).
//  - pbuf stride 40 shorts (80B rows): P b128 reads 8-way -> 2-way (free).

#define NB   4
#define NQL  4096
#define NKL  4096
#define DIM  1024
#define BQ   32
#define BK   32
#define NW   8
#define DSL  128
#define NT   (NKL / BK)
#define LOG2E 1.44269504088896340736f
#define PBW  40            // pbuf row stride in shorts (80 B)

typedef float f32x2 __attribute__((ext_vector_type(2)));
typedef float f32x4 __attribute__((ext_vector_type(4)));
typedef _Float16 f16x8 __attribute__((ext_vector_type(8)));
typedef short s16x8 __attribute__((ext_vector_type(8)));
typedef unsigned int uint_;

union Frag { f16x8 v; s16x8 s; _Float16 h[8]; };

// V LDS addressing (r1-verified): wave-private [BK][DSL] f16 tile, slot-swizzled.
__device__ __forceinline__ int vhi_off(int k, int dloc) {  // byte offset in wave region
    int slot = ((k & 7) + 2 * ((k >> 3) & 3)) & 7;
    return k * (DSL * 2) + ((dloc * 2) ^ (slot * 16));
}

__device__ __forceinline__ void rawbar() {  // LDS visibility only; vmem stays in flight
    asm volatile("s_waitcnt lgkmcnt(0)\n\ts_barrier" ::: "memory");
}

__global__ __attribute__((amdgpu_flat_work_group_size(512, 512),
                          amdgpu_waves_per_eu(2, 2)))
void attn_f16(const float* __restrict__ Qg, const float* __restrict__ Vg,
              float* __restrict__ Og) {
    __shared__ __align__(16) short vhi_s[NW * BK * DSL];  // 64 KB
    __shared__ float spart[NW][BQ][BK];                   // 32 KB (swizzled k idx)
    __shared__ __align__(16) short pbuf[BQ * PBW];        // 2.5 KB (fp16 P)
    __shared__ float mrun[BQ], lrun[BQ], arun[BQ];

    const int tid = (int)threadIdx.x;
    const int l   = tid & 63;
    const int w   = tid >> 6;
    const int l15 = l & 15;
    const int lg  = l >> 4;

    const int b  = (int)blockIdx.x >> 7;
    const int qt = (int)blockIdx.x & 127;
    const int q0 = qt * BQ;
    const int dw = w * DSL;

    if (tid < BQ) { mrun[tid] = -3e38f; lrun[tid] = 0.f; arun[tid] = 1.f; }

    // Q fragments (B-operand): lane holds Q[q0+qb*16+l15][dw+dc*32+lg*8 .. +7] fp16
    f16x8 qf[2][4];
#pragma unroll
    for (int qb = 0; qb < 2; ++qb)
#pragma unroll
        for (int dc = 0; dc < 4; ++dc) {
            const float* qp = Qg + (size_t)(b * NQL + q0 + qb * 16 + l15) * DIM
                            + dw + dc * 32 + lg * 8;
            f32x4 x0 = *(const f32x4*)qp;
            f32x4 x1 = *(const f32x4*)(qp + 4);
            f16x8 a;
#pragma unroll
            for (int j = 0; j < 4; ++j) { a[j] = (_Float16)x0[j]; a[j + 4] = (_Float16)x1[j]; }
            qf[qb][dc] = a;
        }

    f32x4 oacc[2][8];
#pragma unroll
    for (int qb = 0; qb < 2; ++qb)
#pragma unroll
        for (int dg = 0; dg < 8; ++dg)
            oacc[qb][dg] = (f32x4){0.f, 0.f, 0.f, 0.f};

    char* vbase = (char*)&vhi_s[w * (BK * DSL)];

    f32x4 sacc[2][2];
    f32x4 hA[4][2], hB[4][2];  // prefetch buffers (32 VGPR each), live across barriers

    auto loadhalf = [&](f32x4 (&buf)[4][2], int kt_, int kb) {
        const float* vp = Vg + (size_t)(b * NKL + kt_ * BK + kb * 16 + l15) * DIM
                        + dw + lg * 8;
#pragma unroll
        for (int dc = 0; dc < 4; ++dc) {
            buf[dc][0] = *(const f32x4*)(vp + dc * 32);
            buf[dc][1] = *(const f32x4*)(vp + dc * 32 + 4);
        }
    };

    auto computehalf = [&](f32x4 (&buf)[4][2], int kb) {
        const int kvl = kb * 16 + l15;
#pragma unroll
        for (int dc = 0; dc < 4; ++dc) {
            Frag fa;
#pragma unroll
            for (int j = 0; j < 4; ++j) {
                fa.h[j]     = (_Float16)buf[dc][0][j];
                fa.h[j + 4] = (_Float16)buf[dc][1][j];
            }
            *(s16x8*)(vbase + vhi_off(kvl, dc * 32 + lg * 8)) = fa.s;
            sacc[kb][0] = __builtin_amdgcn_mfma_f32_16x16x32_f16(fa.v, qf[0][dc], sacc[kb][0], 0, 0, 0);
            sacc[kb][1] = __builtin_amdgcn_mfma_f32_16x16x32_f16(fa.v, qf[1][dc], sacc[kb][1], 0, 0, 0);
        }
    };

    // softmax assignment: lane handles q = 4w+lg, adjacent k-pair {2*l15, 2*l15+1}
    const int qsm = 4 * w + lg;
    const int kk  = (2 * l15) ^ ((qsm & 7) << 2);   // swizzled read offset (even)

    loadhalf(hA, 0, 0);
    loadhalf(hB, 0, 1);
    rawbar();

    for (int kt = 0; kt < NT; ++kt) {
#pragma unroll
        for (int kb = 0; kb < 2; ++kb)
#pragma unroll
            for (int qb = 0; qb < 2; ++qb)
                sacc[kb][qb] = (f32x4){0.f, 0.f, 0.f, 0.f};

        const int ktn = (kt + 1 < NT) ? kt + 1 : NT - 1;
        computehalf(hA, 0);
        loadhalf(hA, ktn, 0);   // in flight across B1 + softmax + B2 + PV
        computehalf(hB, 1);
        loadhalf(hB, ktn, 1);

        // S^T partials -> spart, b128 stores at XOR-swizzled k-block
        // (acc layout: row k = kb*16+4*lg+r, col q = qb*16+l15; storage idx k^swz)
#pragma unroll
        for (int kb = 0; kb < 2; ++kb)
#pragma unroll
            for (int qb = 0; qb < 2; ++qb) {
                const int q = qb * 16 + l15;
                const int kblk = (kb * 16 + lg * 4) ^ ((q & 7) << 2);
                *(f32x4*)&spart[w][q][kblk] = sacc[kb][qb];
            }
        rawbar();  // B1: LDS visible; prefetch vmem stays in flight

        // Phase 2: reduce over waves (8 b64 reads), __shfl_xor softmax
        {
            f32x2 sp = (f32x2){0.f, 0.f};
#pragma unroll
            for (int wv = 0; wv < NW; ++wv)
                sp += *(const f32x2*)&spart[wv][qsm][kk];
            float s0 = sp[0], s1 = sp[1];   // scores k=2*l15, 2*l15+1
            float mloc = fmaxf(s0, s1);
#pragma unroll
            for (int off = 1; off < 16; off <<= 1)
                mloc = fmaxf(mloc, __shfl_xor(mloc, off));
            float mold = mrun[qsm];
            float mnew = fmaxf(mold, mloc);
            float p0 = exp2f((s0 - mnew) * LOG2E);
            float p1 = exp2f((s1 - mnew) * LOG2E);
            float rs = p0 + p1;
#pragma unroll
            for (int off = 1; off < 16; off <<= 1)
                rs += __shfl_xor(rs, off);
            float alpha = exp2f((mold - mnew) * LOG2E);
            if (l15 == 0) {
                mrun[qsm] = mnew;
                lrun[qsm] = alpha * lrun[qsm] + rs;
                arun[qsm] = alpha;
            }
            // packed fp16 pair at plain k order (one b32 store)
            uint_ pk = (uint_)__builtin_bit_cast(unsigned short, (_Float16)p0)
                     | ((uint_)__builtin_bit_cast(unsigned short, (_Float16)p1) << 16);
            *(uint_*)&pbuf[qsm * PBW + 2 * l15] = pk;
        }
        rawbar();  // B2: P/alpha/m/l visible; prefetch vmem still in flight

        // Phase 3: rescale O by alpha, then O += P * V
        f32x4 av[2];
#pragma unroll
        for (int qb = 0; qb < 2; ++qb)
            av[qb] = *(const f32x4*)&arun[qb * 16 + lg * 4];
#pragma unroll
        for (int qb = 0; qb < 2; ++qb)
#pragma unroll
            for (int dg = 0; dg < 8; ++dg)
#pragma unroll
                for (int r = 0; r < 4; ++r)
                    oacc[qb][dg][r] *= av[qb][r];

        Frag pf[2];
#pragma unroll
        for (int qb = 0; qb < 2; ++qb)
            pf[qb].s = *(const s16x8*)&pbuf[(qb * 16 + l15) * PBW + lg * 8];

#pragma unroll
        for (int dg = 0; dg < 8; ++dg) {
            Frag bf;
#pragma unroll
            for (int j = 0; j < 8; ++j) {
                int k = lg * 8 + j;
                bf.h[j] = *(const _Float16*)(vbase + vhi_off(k, dg * 16 + l15));
            }
            __builtin_amdgcn_s_setprio(1);
#pragma unroll
            for (int qb = 0; qb < 2; ++qb)
                oacc[qb][dg] = __builtin_amdgcn_mfma_f32_16x16x32_f16(
                    pf[qb].v, bf.v, oacc[qb][dg], 0, 0, 0);
            __builtin_amdgcn_s_setprio(0);
        }
    }

    // Epilogue: normalize by l, store fp32
#pragma unroll
    for (int qb = 0; qb < 2; ++qb) {
        f32x4 lv = *(const f32x4*)&lrun[qb * 16 + lg * 4];
        float il[4];
#pragma unroll
        for (int r = 0; r < 4; ++r) il[r] = 1.0f / lv[r];
#pragma unroll
        for (int dg = 0; dg < 8; ++dg)
#pragma unroll
            for (int r = 0; r < 4; ++r) {
                int q = q0 + qb * 16 + lg * 4 + r;
                int d = dw + dg * 16 + l15;
                Og[(size_t)(b * NQL + q) * DIM + d] = oacc[qb][dg][r] * il[r];
            }
    }
}

extern "C" void kernel_launch(void* const* d_in, const int* in_sizes, int n_in,
                              void* d_out, int out_size, void* d_ws, size_t ws_size,
                              hipStream_t stream) {
    const float* Q = (const float*)d_in[0];
    const float* V = (const float*)d_in[1];
    float* O = (float*)d_out;
    (void)in_sizes; (void)n_in; (void)out_size; (void)d_ws; (void)ws_size;
    dim3 grid(NB * (NQL / BQ));  // 512 blocks
    dim3 block(NW * 64);         // 512 threads
    attn_f16<<<grid, block, 0, stream>>>(Q, V, O);
}